// Round 11
// baseline (195.644 us; speedup 1.0000x reference)
//
#include <hip/hip_runtime.h>

typedef __bf16 bf16_t;
typedef __bf16 bf16x4 __attribute__((ext_vector_type(4)));
typedef __bf16 bf16x8 __attribute__((ext_vector_type(8)));
typedef float f32x4 __attribute__((ext_vector_type(4)));
typedef short short4v __attribute__((ext_vector_type(4)));

#define E_DIM 1024
#define S_LEN 1024
#define NHEAD 16
#define HD_DIM 64
#define BATCH 4
#define TOKENS 4096

// ---------------------------------------------------------------- helpers
__device__ __forceinline__ void async_copy16(const void* g, void* l) {
    __builtin_amdgcn_global_load_lds((const __attribute__((address_space(1))) void*)g,
                                     (__attribute__((address_space(3))) void*)l,
                                     16, 0, 0);
}

// PV matmul: 16x16x16 bf16 MFMA (k = quad*4+i matches 16x16 C/D row layout).
__device__ __forceinline__ f32x4 pv_mfma(bf16x4 a, bf16x4 b, f32x4 c) {
#if __has_builtin(__builtin_amdgcn_mfma_f32_16x16x16_bf16)
    return __builtin_amdgcn_mfma_f32_16x16x16_bf16(a, b, c, 0, 0, 0);
#elif __has_builtin(__builtin_amdgcn_mfma_f32_16x16x16bf16_1k)
    short4v as, bs;
    __builtin_memcpy(&as, &a, 8);
    __builtin_memcpy(&bs, &b, 8);
    return __builtin_amdgcn_mfma_f32_16x16x16bf16_1k(as, bs, c, 0, 0, 0);
#else
    f32x4 d;
    asm volatile("v_mfma_f32_16x16x16_bf16 %0, %1, %2, %3\n\ts_nop 7\n\ts_nop 7"
                 : "=v"(d)
                 : "v"(a), "v"(b), "v"(c));
    return d;
#endif
}

// stage one 128x32 A-tile + 128x32 B-tile (bf16 both) into LDS via global_load_lds.
__device__ __forceinline__ void stage_tiles(const bf16_t* gA, const bf16_t* gB,
                                            bf16_t* sAbuf, bf16_t* sBbuf,
                                            int wave, int k0) {
    const int K = 1024;
#pragma unroll
    for (int cc = 0; cc < 4; cc++) {
        int c = wave * 4 + cc;
        if (c < 8)
            async_copy16(gA + (size_t)c * 16 * K + k0, sAbuf + c * 16 * 32);
        else
            async_copy16(gB + (size_t)(c - 8) * 16 * K + k0, sBbuf + (c - 8) * 16 * 32);
    }
}

// ---------------------------------------------------------------- cast: W arrays only (R5-verified)
// X arrays are consumed fp32 directly by proj_gemm. 4 * 2^20 elems -> 2048 blocks.
__global__ __launch_bounds__(256) void cast_w(const float* __restrict__ wq,
                                              const float* __restrict__ wk,
                                              const float* __restrict__ wv,
                                              const float* __restrict__ wo,
                                              bf16_t* __restrict__ dst) {
    const size_t NW = (size_t)E_DIM * E_DIM;  // 2^20
    size_t i = ((size_t)blockIdx.x * 256 + threadIdx.x) * 8;
    int a = (int)(i >> 20);
    const float* src = a == 0 ? wq : (a == 1 ? wk : (a == 2 ? wv : wo));
    size_t off = i & (NW - 1);
    float4 x = *(const float4*)(src + off);
    float4 y = *(const float4*)(src + off + 4);
    bf16x8 o;
    o[0] = (bf16_t)x.x; o[1] = (bf16_t)x.y; o[2] = (bf16_t)x.z; o[3] = (bf16_t)x.w;
    o[4] = (bf16_t)y.x; o[5] = (bf16_t)y.y; o[6] = (bf16_t)y.z; o[7] = (bf16_t)y.w;
    *(bf16x8*)(dst + i) = o;
}

// ---------------------------------------------------------------- batched projection GEMM
// R11 (= R10 resubmit; R10 "container failed twice" attributed to infra — a data race
// would report passed:false, not RuntimeError; both constituents independently
// harness-verified: R5's fp32-direct A staging numerics, R7/R9's counted-vmcnt sync).
// fp32-direct A kills cast_all's 72MB X round-trip; extra staged bytes are OFF the
// critical path under depth-2 counted vmcnt (6 issues/wave/tile -> vmcnt(6)).
// LDS 48KB -> 3 blocks/CU == grid 768 residency. Race audit: vmcnt(6)->barrier makes
// tile globally valid; lgkmcnt(0)->barrier retires all reads before overwrite.
__global__ __launch_bounds__(256, 3) void proj_gemm(const float* __restrict__ Xq,
                                                    const float* __restrict__ Xk,
                                                    const float* __restrict__ Xv,
                                                    const bf16_t* __restrict__ Wq,
                                                    const bf16_t* __restrict__ Wk,
                                                    const bf16_t* __restrict__ Wv,
                                                    bf16_t* __restrict__ Qp,
                                                    bf16_t* __restrict__ Kp,
                                                    bf16_t* __restrict__ Vp) {
    __shared__ float sAf[2][128 * 32];   // 2 x 16KB
    __shared__ bf16_t sB[2][128 * 32];   // 2 x 8KB
    const int z = blockIdx.z;
    const float* A = z == 0 ? Xq : (z == 1 ? Xk : Xv);
    const bf16_t* B = z == 0 ? Wq : (z == 1 ? Wk : Wv);
    bf16_t* C = z == 0 ? Qp : (z == 1 ? Kp : Vp);
    const int N = 1024, K = 1024;
    const int lid = blockIdx.x + 8 * blockIdx.y;
    const int m0 = (((lid & 7) << 2) + ((lid >> 3) & 3)) * 128;
    const int n0 = (lid >> 5) * 128;

    const int tid = threadIdx.x;
    const int wave = tid >> 6, lane = tid & 63;
    const int quad = lane >> 4, l16 = lane & 15;
    const int wm = (wave >> 1) * 64, wn = (wave & 1) * 64;

    // A staging lane map (R5-verified): 8 rows x 8 col-chunks (4 f32 = 16B) per issue;
    // source col-group pre-permuted so the linear-LDS read side lands 4-way (rule #21).
    const int arow = lane >> 3;
    const int acol = ((lane & 7) ^ ((arow & 3) << 1)) * 4;
    // B staging lane map (bf16): 16 rows x 4 col-chunks (8 bf16 = 16B) per issue.
    const int brow = lane >> 2, bcol = (lane & 3) * 8;

    f32x4 acc[4][4];
    const f32x4 vzero = {0.f, 0.f, 0.f, 0.f};
#pragma unroll
    for (int mt = 0; mt < 4; mt++)
#pragma unroll
        for (int nt = 0; nt < 4; nt++) acc[mt][nt] = vzero;

    // stage: 16 A-issues (fp32) + 8 B-issues (bf16) = 24, 6 per wave
#define PROJ_STAGE(buf, k0)                                                          \
    {                                                                                \
        _Pragma("unroll") for (int cc = 0; cc < 6; cc++) {                           \
            int c = wave * 6 + cc;                                                   \
            if (c < 16)                                                              \
                async_copy16(A + (size_t)(m0 + c * 8 + arow) * K + (k0) + acol,      \
                             &sAf[buf][c * 256]);                                    \
            else {                                                                   \
                int cb = c - 16;                                                     \
                async_copy16(B + (size_t)(n0 + cb * 16 + brow) * K + (k0) + bcol,    \
                             &sB[buf][cb * 512]);                                    \
            }                                                                        \
        }                                                                            \
    }

#define PROJ_COMPUTE(cur)                                                            \
    {                                                                                \
        bf16x8 af[4], bfr[4];                                                        \
        _Pragma("unroll") for (int mt = 0; mt < 4; mt++) {                           \
            int r = wm + mt * 16 + l16;                                              \
            const float* pa = &sAf[cur][r * 32 + ((quad ^ (l16 & 3)) * 8)];          \
            f32x4 a0 = *(const f32x4*)pa;                                            \
            f32x4 a1 = *(const f32x4*)(pa + 4);                                      \
            bf16x8 t;                                                                \
            _Pragma("unroll") for (int i = 0; i < 4; i++) {                          \
                t[i] = (bf16_t)a0[i];                                                \
                t[4 + i] = (bf16_t)a1[i];                                            \
            }                                                                        \
            af[mt] = t;                                                              \
        }                                                                            \
        _Pragma("unroll") for (int nt = 0; nt < 4; nt++)                             \
            bfr[nt] = *(const bf16x8*)&sB[cur][(wn + nt * 16 + l16) * 32 + quad * 8];\
        _Pragma("unroll") for (int mt = 0; mt < 4; mt++)                             \
            _Pragma("unroll") for (int nt = 0; nt < 4; nt++)                         \
                acc[mt][nt] = __builtin_amdgcn_mfma_f32_16x16x32_bf16(               \
                    af[mt], bfr[nt], acc[mt][nt], 0, 0, 0);                          \
    }

    // prologue: two tiles in flight (12 outstanding loads/wave)
    PROJ_STAGE(0, 0);
    PROJ_STAGE(1, 32);

    int cur = 0;
#pragma unroll 1
    for (int it = 0; it < 31; ++it) {
        asm volatile("s_waitcnt vmcnt(6)" ::: "memory");  // tile-it retired; tile-(it+1) in flight
        asm volatile("s_barrier" ::: "memory");
        PROJ_COMPUTE(cur);
        asm volatile("s_waitcnt lgkmcnt(0)" ::: "memory");  // all my ds_reads retired
        asm volatile("s_barrier" ::: "memory");             // all waves' reads retired
        int knext = (it + 2) * 32;
        if (knext < K) PROJ_STAGE(cur, knext);
        cur ^= 1;
    }
    // final tile: full drain
    asm volatile("s_waitcnt vmcnt(0)" ::: "memory");
    asm volatile("s_barrier" ::: "memory");
    PROJ_COMPUTE(cur);
#undef PROJ_STAGE
#undef PROJ_COMPUTE

#pragma unroll
    for (int mt = 0; mt < 4; mt++)
#pragma unroll
        for (int nt = 0; nt < 4; nt++)
#pragma unroll
            for (int r = 0; r < 4; r++) {
                int row = m0 + wm + mt * 16 + quad * 4 + r;
                int col = n0 + wn + nt * 16 + l16;
                C[(size_t)row * N + col] = (bf16_t)acc[mt][nt][r];
            }
}

// ---------------------------------------------------------------- output GEMM (R9-verified 3-deep counted-vmcnt)
__global__ __launch_bounds__(256, 3) void out_gemm(const bf16_t* __restrict__ A,
                                                   const bf16_t* __restrict__ B,
                                                   float* __restrict__ C) {
    __shared__ bf16_t sA[3][128 * 32];
    __shared__ bf16_t sB[3][128 * 32];
    const int N = 1024, K = 1024;
    const int lid = blockIdx.x + 8 * blockIdx.y;
    const int m0 = (((lid & 7) << 2) + ((lid >> 3) & 3)) * 128;
    const int n0 = (lid >> 5) * 128;

    const int tid = threadIdx.x;
    const int wave = tid >> 6, lane = tid & 63;
    const int quad = lane >> 4, l16 = lane & 15;
    const int wm = (wave >> 1) * 64, wn = (wave & 1) * 64;
    const int srow = lane >> 2, scol = (lane & 3) * 8;

    const bf16_t* gA = A + (size_t)(m0 + srow) * K + scol;
    const bf16_t* gB = B + (size_t)(n0 + srow) * K + scol;

    f32x4 acc[4][4];
    const f32x4 vzero = {0.f, 0.f, 0.f, 0.f};
#pragma unroll
    for (int mt = 0; mt < 4; mt++)
#pragma unroll
        for (int nt = 0; nt < 4; nt++) acc[mt][nt] = vzero;

#define OUT_COMPUTE(cur)                                                              \
    {                                                                                 \
        bf16x8 af[4], bfr[4];                                                         \
        _Pragma("unroll") for (int mt = 0; mt < 4; mt++)                              \
            af[mt] = *(const bf16x8*)&sA[cur][(wm + mt * 16 + l16) * 32 + quad * 8];  \
        _Pragma("unroll") for (int nt = 0; nt < 4; nt++)                              \
            bfr[nt] = *(const bf16x8*)&sB[cur][(wn + nt * 16 + l16) * 32 + quad * 8]; \
        _Pragma("unroll") for (int mt = 0; mt < 4; mt++)                              \
            _Pragma("unroll") for (int nt = 0; nt < 4; nt++)                          \
                acc[mt][nt] = __builtin_amdgcn_mfma_f32_16x16x32_bf16(                \
                    af[mt], bfr[nt], acc[mt][nt], 0, 0, 0);                           \
    }

    stage_tiles(gA, gB, sA[0], sB[0], wave, 0);
    stage_tiles(gA, gB, sA[1], sB[1], wave, 32);
    stage_tiles(gA, gB, sA[2], sB[2], wave, 64);

    int cur = 0;
#pragma unroll 1
    for (int it = 0; it < 29; ++it) {
        asm volatile("s_waitcnt vmcnt(8)" ::: "memory");
        asm volatile("s_barrier" ::: "memory");
        OUT_COMPUTE(cur);
        asm volatile("s_waitcnt lgkmcnt(0)" ::: "memory");
        asm volatile("s_barrier" ::: "memory");
        stage_tiles(gA, gB, sA[cur], sB[cur], wave, (it + 3) * 32);
        cur = cur == 2 ? 0 : cur + 1;
    }
    asm volatile("s_waitcnt vmcnt(8)" ::: "memory");
    asm volatile("s_barrier" ::: "memory");
    OUT_COMPUTE(cur);
    cur = cur == 2 ? 0 : cur + 1;
    asm volatile("s_waitcnt vmcnt(4)" ::: "memory");
    asm volatile("s_barrier" ::: "memory");
    OUT_COMPUTE(cur);
    cur = cur == 2 ? 0 : cur + 1;
    asm volatile("s_waitcnt vmcnt(0)" ::: "memory");
    asm volatile("s_barrier" ::: "memory");
    OUT_COMPUTE(cur);
#undef OUT_COMPUTE

#pragma unroll
    for (int mt = 0; mt < 4; mt++)
#pragma unroll
        for (int nt = 0; nt < 4; nt++)
#pragma unroll
            for (int r = 0; r < 4; r++) {
                int row = m0 + wm + mt * 16 + quad * 4 + r;
                int col = n0 + wn + nt * 16 + l16;
                C[(size_t)row * N + col] = acc[mt][nt][r];
            }
}

// ---------------------------------------------------------------- flash attention v4 (R7/R9-verified, frozen)
#define KP 72

__global__ __launch_bounds__(256, 2) void flash_attn(const bf16_t* __restrict__ Q,
                                                     const bf16_t* __restrict__ K,
                                                     const bf16_t* __restrict__ V,
                                                     bf16_t* __restrict__ O) {
    __shared__ bf16_t smem[2 * 64 * KP];  // sK | sVt; reused as epilogue scratch
    bf16_t* sK = smem;
    bf16_t* sVt = smem + 64 * KP;

    const int tid = threadIdx.x;
    const int wave = tid >> 6, lane = tid & 63;
    const int quad = lane >> 4, l16 = lane & 15;
    const int qt = blockIdx.y >> 1;
    const int h = blockIdx.x * 2 + (blockIdx.y & 1);  // XCD = bx -> 2 heads/XCD (KV L2-resident)
    const int b = blockIdx.z;
    const size_t base = (size_t)b * S_LEN * E_DIM + h * HD_DIM;
    const float c_exp = 0.125f * 1.44269504089f;  // scale * log2(e)

    // Q fragments (B-operand of QK^T): lane = q-row l16, k = quad*8+i
    bf16x8 qf[2][2];
#pragma unroll
    for (int mt = 0; mt < 2; mt++) {
        const bf16_t* qp =
            Q + base + (size_t)(qt * 128 + wave * 32 + mt * 16 + l16) * E_DIM + quad * 8;
        qf[mt][0] = *(const bf16x8*)qp;
        qf[mt][1] = *(const bf16x8*)(qp + 32);
    }

    float lsum[2] = {0.f, 0.f};
    f32x4 acc[2][4];
    const f32x4 vzero = {0.f, 0.f, 0.f, 0.f};
#pragma unroll
    for (int mt = 0; mt < 2; mt++)
#pragma unroll
        for (int dt = 0; dt < 4; dt++) acc[mt][dt] = vzero;

    const int stg = tid & 7;  // staging d-group (d>>3)

    for (int j0 = 0; j0 < S_LEN; j0 += 64) {
        __syncthreads();
#pragma unroll
        for (int it = 0; it < 2; it++) {
            int r = (tid >> 3) + it * 32;  // key row 0..63
            int c = stg * 8;               // d col
            bf16x8 kv = *(const bf16x8*)(K + base + (size_t)(j0 + r) * E_DIM + c);
            *(bf16x8*)&sK[r * KP + c] = kv;
            bf16x8 vv = *(const bf16x8*)(V + base + (size_t)(j0 + r) * E_DIM + c);
            int jb = (((r >> 2) ^ stg) << 2) | (r & 3);  // 4-chunk XOR, key = d>>3 = stg
#pragma unroll
            for (int i = 0; i < 8; i++) sVt[(c + i) * KP + jb] = vv[i];
        }
        __syncthreads();

        // K fragments (A-operand: lane = j-row l16, k = quad*8+i)
        bf16x8 kf[4][2];
#pragma unroll
        for (int jt = 0; jt < 4; jt++) {
            kf[jt][0] = *(const bf16x8*)&sK[(jt * 16 + l16) * KP + quad * 8];
            kf[jt][1] = *(const bf16x8*)&sK[(jt * 16 + l16) * KP + 32 + quad * 8];
        }

        // S^T = K Q^T; exp2 -> P kept in registers (16x16x16 B-operand layout)
        bf16x4 pb[2][4];
#pragma unroll
        for (int mt = 0; mt < 2; mt++)
#pragma unroll
            for (int jt = 0; jt < 4; jt++) {
                f32x4 s = vzero;
                s = __builtin_amdgcn_mfma_f32_16x16x32_bf16(kf[jt][0], qf[mt][0], s, 0, 0, 0);
                s = __builtin_amdgcn_mfma_f32_16x16x32_bf16(kf[jt][1], qf[mt][1], s, 0, 0, 0);
#pragma unroll
                for (int r = 0; r < 4; r++) {
                    float p = __builtin_amdgcn_exp2f(s[r] * c_exp);
                    lsum[mt] += p;
                    pb[mt][jt][r] = (bf16_t)p;
                }
            }

        // ctx^T += V^T P^T via 16x16x16: A = V^T rows d (k=j quad*4+i), B = pb
#pragma unroll
        for (int jt = 0; jt < 4; jt++)
#pragma unroll
            for (int dt = 0; dt < 4; dt++) {
                int cidx = (jt * 4 + quad) ^ (dt * 2 + (l16 >> 3));
                bf16x4 vf = *(const bf16x4*)&sVt[(dt * 16 + l16) * KP + cidx * 4];
#pragma unroll
                for (int mt = 0; mt < 2; mt++)
                    acc[mt][dt] = pv_mfma(vf, pb[mt][jt], acc[mt][dt]);
            }
    }

    // lsum: reduce across quads (q = l16 common)
    float inv[2];
#pragma unroll
    for (int mt = 0; mt < 2; mt++) {
        lsum[mt] += __shfl_xor(lsum[mt], 16);
        lsum[mt] += __shfl_xor(lsum[mt], 32);
        inv[mt] = __builtin_amdgcn_rcpf(lsum[mt]);
    }

    // epilogue: ctx^T (d=dt*16+quad*4+r, q=mt*16+l16) -> LDS transpose -> coalesced O
    __syncthreads();  // all waves done reading sK/sVt
    bf16_t* ep = smem + wave * 32 * KP;  // wave-private 32 q-rows x 72
#pragma unroll
    for (int mt = 0; mt < 2; mt++)
#pragma unroll
        for (int dt = 0; dt < 4; dt++)
#pragma unroll
            for (int r = 0; r < 4; r++)
                ep[(mt * 16 + l16) * KP + dt * 16 + quad * 4 + r] =
                    (bf16_t)(acc[mt][dt][r] * inv[mt]);
    // same-wave readback (compiler inserts lgkmcnt wait), coalesced 16B stores
#pragma unroll
    for (int mt = 0; mt < 2; mt++)
#pragma unroll
        for (int c = 0; c < 2; c++) {
            int row = lane >> 2;
            int col = (lane & 3) * 8 + c * 32;
            bf16x8 oval = *(const bf16x8*)&ep[(mt * 16 + row) * KP + col];
            *(bf16x8*)&O[base + (size_t)(qt * 128 + wave * 32 + mt * 16 + row) * E_DIM + col] =
                oval;
        }
}

// ---------------------------------------------------------------- launch
extern "C" void kernel_launch(void* const* d_in, const int* in_sizes, int n_in,
                              void* d_out, int out_size, void* d_ws, size_t ws_size,
                              hipStream_t stream) {
    const float* q  = (const float*)d_in[0];
    const float* k  = (const float*)d_in[1];
    const float* v  = (const float*)d_in[2];
    const float* wq = (const float*)d_in[3];
    const float* wk = (const float*)d_in[4];
    const float* wv = (const float*)d_in[5];
    const float* wo = (const float*)d_in[6];
    float* out = (float*)d_out;

    const int NX = TOKENS * E_DIM;  // 4M elems
    const int NW = E_DIM * E_DIM;   // 1M elems

    bf16_t* ws  = (bf16_t*)d_ws;
    bf16_t* Wqb = ws;                    // 1M
    bf16_t* Wkb = Wqb + NW;
    bf16_t* Wvb = Wkb + NW;
    bf16_t* Wob = Wvb + NW;
    bf16_t* Qp  = Wob + NW;              // 4M
    bf16_t* Kp  = Qp + (size_t)NX;       // 4M
    bf16_t* Vp  = Kp + (size_t)NX;       // 4M
    bf16_t* ctx = Vp + (size_t)NX;       // 4M

    // W casts only: 4*NW = 4M elems -> 2048 blocks
    cast_w<<<2048, 256, 0, stream>>>(wq, wk, wv, wo, Wqb);

    // batched projections: fp32-direct A, depth-2 counted-vmcnt (XCD-swizzled)
    proj_gemm<<<dim3(8, 32, 3), 256, 0, stream>>>(q, k, v, Wqb, Wkb, Wvb, Qp, Kp, Vp);

    // attention: grid (8,16,4); h-grouped XCD swizzle inside (R7/R9-verified v4)
    flash_attn<<<dim3(8, 16, 4), 256, 0, stream>>>(Qp, Kp, Vp, ctx);

    // output projection (XCD-swizzled, 3-deep counted-vmcnt) -> fp32 d_out
    out_gemm<<<dim3(8, 32), 256, 0, stream>>>(ctx, Wob, out);
}

// Round 12
// 184.166 us; speedup vs baseline: 1.0623x; 1.0623x over previous
//
#include <hip/hip_runtime.h>

typedef __bf16 bf16_t;
typedef __bf16 bf16x4 __attribute__((ext_vector_type(4)));
typedef __bf16 bf16x8 __attribute__((ext_vector_type(8)));
typedef float f32x4 __attribute__((ext_vector_type(4)));
typedef short short4v __attribute__((ext_vector_type(4)));

#define E_DIM 1024
#define S_LEN 1024
#define NHEAD 16
#define HD_DIM 64
#define BATCH 4
#define TOKENS 4096

// ---------------------------------------------------------------- helpers
__device__ __forceinline__ void async_copy16(const bf16_t* g, bf16_t* l) {
    __builtin_amdgcn_global_load_lds((const __attribute__((address_space(1))) void*)g,
                                     (__attribute__((address_space(3))) void*)l,
                                     16, 0, 0);
}

// PV matmul: 16x16x16 bf16 MFMA (k = quad*4+i matches 16x16 C/D row layout).
__device__ __forceinline__ f32x4 pv_mfma(bf16x4 a, bf16x4 b, f32x4 c) {
#if __has_builtin(__builtin_amdgcn_mfma_f32_16x16x16_bf16)
    return __builtin_amdgcn_mfma_f32_16x16x16_bf16(a, b, c, 0, 0, 0);
#elif __has_builtin(__builtin_amdgcn_mfma_f32_16x16x16bf16_1k)
    short4v as, bs;
    __builtin_memcpy(&as, &a, 8);
    __builtin_memcpy(&bs, &b, 8);
    return __builtin_amdgcn_mfma_f32_16x16x16bf16_1k(as, bs, c, 0, 0, 0);
#else
    f32x4 d;
    asm volatile("v_mfma_f32_16x16x16_bf16 %0, %1, %2, %3\n\ts_nop 7\n\ts_nop 7"
                 : "=v"(d)
                 : "v"(a), "v"(b), "v"(c));
    return d;
#endif
}

// stage one 128x32 A-tile + 128x32 B-tile (bf16) into LDS via global_load_lds.
// 16 issues total, 4 per wave -> per-wave vmcnt tracks 4 loads per tile.
__device__ __forceinline__ void stage_tiles(const bf16_t* gA, const bf16_t* gB,
                                            bf16_t* sAbuf, bf16_t* sBbuf,
                                            int wave, int k0) {
    const int K = 1024;
#pragma unroll
    for (int cc = 0; cc < 4; cc++) {
        int c = wave * 4 + cc;
        if (c < 8)
            async_copy16(gA + (size_t)c * 16 * K + k0, sAbuf + c * 16 * 32);
        else
            async_copy16(gB + (size_t)(c - 8) * 16 * K + k0, sBbuf + (c - 8) * 16 * 32);
    }
}

// ---------------------------------------------------------------- fused cast: all 7 arrays (R1-verified)
__global__ __launch_bounds__(256) void cast_all(const float* __restrict__ q,
                                                const float* __restrict__ k,
                                                const float* __restrict__ v,
                                                const float* __restrict__ wq,
                                                const float* __restrict__ wk,
                                                const float* __restrict__ wv,
                                                const float* __restrict__ wo,
                                                bf16_t* __restrict__ dst) {
    const size_t NX = (size_t)TOKENS * E_DIM;  // 2^22
    const size_t NW = (size_t)E_DIM * E_DIM;   // 2^20
    size_t i = ((size_t)blockIdx.x * 256 + threadIdx.x) * 8;
    const float* src;
    size_t off;
    if (i < 3 * NX) {
        int a = (int)(i >> 22);
        src = a == 0 ? q : (a == 1 ? k : v);
        off = i & (NX - 1);
    } else {
        size_t j = i - 3 * NX;
        int a = (int)(j >> 20);
        src = a == 0 ? wq : (a == 1 ? wk : (a == 2 ? wv : wo));
        off = j & (NW - 1);
    }
    float4 x = *(const float4*)(src + off);
    float4 y = *(const float4*)(src + off + 4);
    bf16x8 o;
    o[0] = (bf16_t)x.x; o[1] = (bf16_t)x.y; o[2] = (bf16_t)x.z; o[3] = (bf16_t)x.w;
    o[4] = (bf16_t)y.x; o[5] = (bf16_t)y.y; o[6] = (bf16_t)y.z; o[7] = (bf16_t)y.w;
    *(bf16x8*)(dst + i) = o;
}

// ---------------------------------------------------------------- batched projection GEMM (R9-verified 3-deep counted-vmcnt)
__global__ __launch_bounds__(256, 3) void proj_gemm(const bf16_t* __restrict__ Xq,
                                                    const bf16_t* __restrict__ Xk,
                                                    const bf16_t* __restrict__ Xv,
                                                    const bf16_t* __restrict__ Wq,
                                                    const bf16_t* __restrict__ Wk,
                                                    const bf16_t* __restrict__ Wv,
                                                    bf16_t* __restrict__ Qp,
                                                    bf16_t* __restrict__ Kp,
                                                    bf16_t* __restrict__ Vp) {
    __shared__ bf16_t sA[3][128 * 32];
    __shared__ bf16_t sB[3][128 * 32];
    const int z = blockIdx.z;
    const bf16_t* A = z == 0 ? Xq : (z == 1 ? Xk : Xv);
    const bf16_t* B = z == 0 ? Wq : (z == 1 ? Wk : Wv);
    bf16_t* C = z == 0 ? Qp : (z == 1 ? Kp : Vp);
    const int N = 1024, K = 1024;
    const int lid = blockIdx.x + 8 * blockIdx.y;
    const int m0 = (((lid & 7) << 2) + ((lid >> 3) & 3)) * 128;
    const int n0 = (lid >> 5) * 128;

    const int tid = threadIdx.x;
    const int wave = tid >> 6, lane = tid & 63;
    const int quad = lane >> 4, l16 = lane & 15;
    const int wm = (wave >> 1) * 64, wn = (wave & 1) * 64;
    const int srow = lane >> 2, scol = (lane & 3) * 8;

    const bf16_t* gA = A + (size_t)(m0 + srow) * K + scol;
    const bf16_t* gB = B + (size_t)(n0 + srow) * K + scol;

    f32x4 acc[4][4];
    const f32x4 vzero = {0.f, 0.f, 0.f, 0.f};
#pragma unroll
    for (int mt = 0; mt < 4; mt++)
#pragma unroll
        for (int nt = 0; nt < 4; nt++) acc[mt][nt] = vzero;

#define PROJ_COMPUTE(cur)                                                             \
    {                                                                                 \
        bf16x8 af[4], bfr[4];                                                         \
        _Pragma("unroll") for (int mt = 0; mt < 4; mt++)                              \
            af[mt] = *(const bf16x8*)&sA[cur][(wm + mt * 16 + l16) * 32 + quad * 8];  \
        _Pragma("unroll") for (int nt = 0; nt < 4; nt++)                              \
            bfr[nt] = *(const bf16x8*)&sB[cur][(wn + nt * 16 + l16) * 32 + quad * 8]; \
        _Pragma("unroll") for (int mt = 0; mt < 4; mt++)                              \
            _Pragma("unroll") for (int nt = 0; nt < 4; nt++)                          \
                acc[mt][nt] = __builtin_amdgcn_mfma_f32_16x16x32_bf16(                \
                    af[mt], bfr[nt], acc[mt][nt], 0, 0, 0);                           \
    }

    // prologue: three tiles in flight (12 outstanding loads/wave)
    stage_tiles(gA, gB, sA[0], sB[0], wave, 0);
    stage_tiles(gA, gB, sA[1], sB[1], wave, 32);
    stage_tiles(gA, gB, sA[2], sB[2], wave, 64);

    int cur = 0;
#pragma unroll 1
    for (int it = 0; it < 29; ++it) {
        asm volatile("s_waitcnt vmcnt(8)" ::: "memory");  // tile-it retired; it+1,it+2 in flight
        asm volatile("s_barrier" ::: "memory");
        PROJ_COMPUTE(cur);
        asm volatile("s_waitcnt lgkmcnt(0)" ::: "memory");  // all my ds_reads retired
        asm volatile("s_barrier" ::: "memory");             // all waves' reads retired
        stage_tiles(gA, gB, sA[cur], sB[cur], wave, (it + 3) * 32);  // (it+3)*32 <= 992 < K
        cur = cur == 2 ? 0 : cur + 1;
    }
    // tile 29 (outstanding 12), tile 30 (8), tile 31 (4)
    asm volatile("s_waitcnt vmcnt(8)" ::: "memory");
    asm volatile("s_barrier" ::: "memory");
    PROJ_COMPUTE(cur);
    cur = cur == 2 ? 0 : cur + 1;
    asm volatile("s_waitcnt vmcnt(4)" ::: "memory");
    asm volatile("s_barrier" ::: "memory");
    PROJ_COMPUTE(cur);
    cur = cur == 2 ? 0 : cur + 1;
    asm volatile("s_waitcnt vmcnt(0)" ::: "memory");
    asm volatile("s_barrier" ::: "memory");
    PROJ_COMPUTE(cur);
#undef PROJ_COMPUTE

#pragma unroll
    for (int mt = 0; mt < 4; mt++)
#pragma unroll
        for (int nt = 0; nt < 4; nt++)
#pragma unroll
            for (int r = 0; r < 4; r++) {
                int row = m0 + wm + mt * 16 + quad * 4 + r;
                int col = n0 + wn + nt * 16 + l16;
                C[(size_t)row * N + col] = (bf16_t)acc[mt][nt][r];
            }
}

// ---------------------------------------------------------------- output GEMM (R9-verified 3-deep counted-vmcnt)
__global__ __launch_bounds__(256, 3) void out_gemm(const bf16_t* __restrict__ A,
                                                   const bf16_t* __restrict__ B,
                                                   float* __restrict__ C) {
    __shared__ bf16_t sA[3][128 * 32];
    __shared__ bf16_t sB[3][128 * 32];
    const int N = 1024, K = 1024;
    const int lid = blockIdx.x + 8 * blockIdx.y;
    const int m0 = (((lid & 7) << 2) + ((lid >> 3) & 3)) * 128;
    const int n0 = (lid >> 5) * 128;

    const int tid = threadIdx.x;
    const int wave = tid >> 6, lane = tid & 63;
    const int quad = lane >> 4, l16 = lane & 15;
    const int wm = (wave >> 1) * 64, wn = (wave & 1) * 64;
    const int srow = lane >> 2, scol = (lane & 3) * 8;

    const bf16_t* gA = A + (size_t)(m0 + srow) * K + scol;
    const bf16_t* gB = B + (size_t)(n0 + srow) * K + scol;

    f32x4 acc[4][4];
    const f32x4 vzero = {0.f, 0.f, 0.f, 0.f};
#pragma unroll
    for (int mt = 0; mt < 4; mt++)
#pragma unroll
        for (int nt = 0; nt < 4; nt++) acc[mt][nt] = vzero;

#define OUT_COMPUTE(cur)                                                              \
    {                                                                                 \
        bf16x8 af[4], bfr[4];                                                         \
        _Pragma("unroll") for (int mt = 0; mt < 4; mt++)                              \
            af[mt] = *(const bf16x8*)&sA[cur][(wm + mt * 16 + l16) * 32 + quad * 8];  \
        _Pragma("unroll") for (int nt = 0; nt < 4; nt++)                              \
            bfr[nt] = *(const bf16x8*)&sB[cur][(wn + nt * 16 + l16) * 32 + quad * 8]; \
        _Pragma("unroll") for (int mt = 0; mt < 4; mt++)                              \
            _Pragma("unroll") for (int nt = 0; nt < 4; nt++)                          \
                acc[mt][nt] = __builtin_amdgcn_mfma_f32_16x16x32_bf16(                \
                    af[mt], bfr[nt], acc[mt][nt], 0, 0, 0);                           \
    }

    stage_tiles(gA, gB, sA[0], sB[0], wave, 0);
    stage_tiles(gA, gB, sA[1], sB[1], wave, 32);
    stage_tiles(gA, gB, sA[2], sB[2], wave, 64);

    int cur = 0;
#pragma unroll 1
    for (int it = 0; it < 29; ++it) {
        asm volatile("s_waitcnt vmcnt(8)" ::: "memory");
        asm volatile("s_barrier" ::: "memory");
        OUT_COMPUTE(cur);
        asm volatile("s_waitcnt lgkmcnt(0)" ::: "memory");
        asm volatile("s_barrier" ::: "memory");
        stage_tiles(gA, gB, sA[cur], sB[cur], wave, (it + 3) * 32);
        cur = cur == 2 ? 0 : cur + 1;
    }
    asm volatile("s_waitcnt vmcnt(8)" ::: "memory");
    asm volatile("s_barrier" ::: "memory");
    OUT_COMPUTE(cur);
    cur = cur == 2 ? 0 : cur + 1;
    asm volatile("s_waitcnt vmcnt(4)" ::: "memory");
    asm volatile("s_barrier" ::: "memory");
    OUT_COMPUTE(cur);
    cur = cur == 2 ? 0 : cur + 1;
    asm volatile("s_waitcnt vmcnt(0)" ::: "memory");
    asm volatile("s_barrier" ::: "memory");
    OUT_COMPUTE(cur);
#undef OUT_COMPUTE

#pragma unroll
    for (int mt = 0; mt < 4; mt++)
#pragma unroll
        for (int nt = 0; nt < 4; nt++)
#pragma unroll
            for (int r = 0; r < 4; r++) {
                int row = m0 + wm + mt * 16 + quad * 4 + r;
                int col = n0 + wn + nt * 16 + l16;
                C[(size_t)row * N + col] = acc[mt][nt][r];
            }
}

// ---------------------------------------------------------------- flash attention v4.1
// R12: R7/R9-verified v4 with ONE change — lsum accumulated in f32x4 (4 independent
// lanes) instead of a scalar. The scalar form is a 16-deep dependent add chain per
// mt per j-tile (~128cy serial, un-hidable at 2 waves/SIMD); vector form cuts the
// chain 4x. Horizontal sum folded in at the end. Pure reassociation of a positive
// sum — numerically harmless.
#define KP 72

__global__ __launch_bounds__(256, 2) void flash_attn(const bf16_t* __restrict__ Q,
                                                     const bf16_t* __restrict__ K,
                                                     const bf16_t* __restrict__ V,
                                                     bf16_t* __restrict__ O) {
    __shared__ bf16_t smem[2 * 64 * KP];  // sK | sVt; reused as epilogue scratch
    bf16_t* sK = smem;
    bf16_t* sVt = smem + 64 * KP;

    const int tid = threadIdx.x;
    const int wave = tid >> 6, lane = tid & 63;
    const int quad = lane >> 4, l16 = lane & 15;
    const int qt = blockIdx.y >> 1;
    const int h = blockIdx.x * 2 + (blockIdx.y & 1);  // XCD = bx -> 2 heads/XCD (KV L2-resident)
    const int b = blockIdx.z;
    const size_t base = (size_t)b * S_LEN * E_DIM + h * HD_DIM;
    const float c_exp = 0.125f * 1.44269504089f;  // scale * log2(e)

    // Q fragments (B-operand of QK^T): lane = q-row l16, k = quad*8+i
    bf16x8 qf[2][2];
#pragma unroll
    for (int mt = 0; mt < 2; mt++) {
        const bf16_t* qp =
            Q + base + (size_t)(qt * 128 + wave * 32 + mt * 16 + l16) * E_DIM + quad * 8;
        qf[mt][0] = *(const bf16x8*)qp;
        qf[mt][1] = *(const bf16x8*)(qp + 32);
    }

    const f32x4 vzero = {0.f, 0.f, 0.f, 0.f};
    f32x4 lsum4[2] = {vzero, vzero};  // 4 independent accumulators per mt
    f32x4 acc[2][4];
#pragma unroll
    for (int mt = 0; mt < 2; mt++)
#pragma unroll
        for (int dt = 0; dt < 4; dt++) acc[mt][dt] = vzero;

    const int stg = tid & 7;  // staging d-group (d>>3)

    for (int j0 = 0; j0 < S_LEN; j0 += 64) {
        __syncthreads();
#pragma unroll
        for (int it = 0; it < 2; it++) {
            int r = (tid >> 3) + it * 32;  // key row 0..63
            int c = stg * 8;               // d col
            bf16x8 kv = *(const bf16x8*)(K + base + (size_t)(j0 + r) * E_DIM + c);
            *(bf16x8*)&sK[r * KP + c] = kv;
            bf16x8 vv = *(const bf16x8*)(V + base + (size_t)(j0 + r) * E_DIM + c);
            int jb = (((r >> 2) ^ stg) << 2) | (r & 3);  // 4-chunk XOR, key = d>>3 = stg
#pragma unroll
            for (int i = 0; i < 8; i++) sVt[(c + i) * KP + jb] = vv[i];
        }
        __syncthreads();

        // K fragments (A-operand: lane = j-row l16, k = quad*8+i)
        bf16x8 kf[4][2];
#pragma unroll
        for (int jt = 0; jt < 4; jt++) {
            kf[jt][0] = *(const bf16x8*)&sK[(jt * 16 + l16) * KP + quad * 8];
            kf[jt][1] = *(const bf16x8*)&sK[(jt * 16 + l16) * KP + 32 + quad * 8];
        }

        // S^T = K Q^T; exp2 -> P kept in registers (16x16x16 B-operand layout)
        bf16x4 pb[2][4];
#pragma unroll
        for (int mt = 0; mt < 2; mt++)
#pragma unroll
            for (int jt = 0; jt < 4; jt++) {
                f32x4 s = vzero;
                s = __builtin_amdgcn_mfma_f32_16x16x32_bf16(kf[jt][0], qf[mt][0], s, 0, 0, 0);
                s = __builtin_amdgcn_mfma_f32_16x16x32_bf16(kf[jt][1], qf[mt][1], s, 0, 0, 0);
#pragma unroll
                for (int r = 0; r < 4; r++) {
                    float p = __builtin_amdgcn_exp2f(s[r] * c_exp);
                    lsum4[mt][r] += p;  // independent per-r chains (4-deep, not 16-deep)
                    pb[mt][jt][r] = (bf16_t)p;
                }
            }

        // ctx^T += V^T P^T via 16x16x16: A = V^T rows d (k=j quad*4+i), B = pb
#pragma unroll
        for (int jt = 0; jt < 4; jt++)
#pragma unroll
            for (int dt = 0; dt < 4; dt++) {
                int cidx = (jt * 4 + quad) ^ (dt * 2 + (l16 >> 3));
                bf16x4 vf = *(const bf16x4*)&sVt[(dt * 16 + l16) * KP + cidx * 4];
#pragma unroll
                for (int mt = 0; mt < 2; mt++)
                    acc[mt][dt] = pv_mfma(vf, pb[mt][jt], acc[mt][dt]);
            }
    }

    // lsum: horizontal fold then reduce across quads (q = l16 common)
    float inv[2];
#pragma unroll
    for (int mt = 0; mt < 2; mt++) {
        float l = (lsum4[mt][0] + lsum4[mt][1]) + (lsum4[mt][2] + lsum4[mt][3]);
        l += __shfl_xor(l, 16);
        l += __shfl_xor(l, 32);
        inv[mt] = __builtin_amdgcn_rcpf(l);
    }

    // epilogue: ctx^T (d=dt*16+quad*4+r, q=mt*16+l16) -> LDS transpose -> coalesced O
    __syncthreads();  // all waves done reading sK/sVt
    bf16_t* ep = smem + wave * 32 * KP;  // wave-private 32 q-rows x 72
#pragma unroll
    for (int mt = 0; mt < 2; mt++)
#pragma unroll
        for (int dt = 0; dt < 4; dt++)
#pragma unroll
            for (int r = 0; r < 4; r++)
                ep[(mt * 16 + l16) * KP + dt * 16 + quad * 4 + r] =
                    (bf16_t)(acc[mt][dt][r] * inv[mt]);
    // same-wave readback (compiler inserts lgkmcnt wait), coalesced 16B stores
#pragma unroll
    for (int mt = 0; mt < 2; mt++)
#pragma unroll
        for (int c = 0; c < 2; c++) {
            int row = lane >> 2;
            int col = (lane & 3) * 8 + c * 32;
            bf16x8 oval = *(const bf16x8*)&ep[(mt * 16 + row) * KP + col];
            *(bf16x8*)&O[base + (size_t)(qt * 128 + wave * 32 + mt * 16 + row) * E_DIM + col] =
                oval;
        }
}

// ---------------------------------------------------------------- launch
extern "C" void kernel_launch(void* const* d_in, const int* in_sizes, int n_in,
                              void* d_out, int out_size, void* d_ws, size_t ws_size,
                              hipStream_t stream) {
    const float* q  = (const float*)d_in[0];
    const float* k  = (const float*)d_in[1];
    const float* v  = (const float*)d_in[2];
    const float* wq = (const float*)d_in[3];
    const float* wk = (const float*)d_in[4];
    const float* wv = (const float*)d_in[5];
    const float* wo = (const float*)d_in[6];
    float* out = (float*)d_out;

    const int NX = TOKENS * E_DIM;  // 4M elems
    const int NW = E_DIM * E_DIM;   // 1M elems

    bf16_t* ws  = (bf16_t*)d_ws;
    bf16_t* Xq  = ws;                    // 4M
    bf16_t* Xk  = ws + (size_t)NX;       // 4M
    bf16_t* Xv  = ws + (size_t)2 * NX;   // 4M
    bf16_t* Wqb = ws + (size_t)3 * NX;   // 1M
    bf16_t* Wkb = Wqb + NW;
    bf16_t* Wvb = Wkb + NW;
    bf16_t* Wob = Wvb + NW;
    bf16_t* Qp  = Wob + NW;              // 4M
    bf16_t* Kp  = Qp + (size_t)NX;       // 4M
    bf16_t* Vp  = Kp + (size_t)NX;       // 4M
    bf16_t* ctx = Xq;                    // reuse: Xq dead after projections

    // fused casts: 3*NX + 4*NW = 16M elems -> 8192 blocks
    cast_all<<<8192, 256, 0, stream>>>(q, k, v, wq, wk, wv, wo, Xq);

    // batched projections (XCD-swizzled, 3-deep counted-vmcnt, R9-verified)
    proj_gemm<<<dim3(8, 32, 3), 256, 0, stream>>>(Xq, Xk, Xv, Wqb, Wkb, Wvb, Qp, Kp, Vp);

    // attention: grid (8,16,4); v4 + vectorized lsum
    flash_attn<<<dim3(8, 16, 4), 256, 0, stream>>>(Qp, Kp, Vp, ctx);

    // output projection (XCD-swizzled, 3-deep counted-vmcnt, R9-verified) -> fp32 d_out
    out_gemm<<<dim3(8, 32), 256, 0, stream>>>(ctx, Wob, out);
}